// Round 6
// baseline (288.603 us; speedup 1.0000x reference)
//
#include <hip/hip_runtime.h>
#include <cstdint>
#include <cstddef>

typedef unsigned int u32;
typedef unsigned short u16;
typedef __bf16 bf16x8 __attribute__((ext_vector_type(8)));
typedef float f32x4 __attribute__((ext_vector_type(4)));
typedef u16 u16x8 __attribute__((ext_vector_type(8)));

static constexpr int T_TOK = 4096;
static constexpr int HID   = 2048;
static constexpr int INTER = 1024;
static constexpr int NEXP  = 8;
static constexpr int TOPK  = 2;
static constexpr int SLOT_CAP = 10240;          // 8192 real + per-expert 256-align pad
static constexpr int NT_M = SLOT_CAP / 256;     // 40 m-tiles

static constexpr int META_TOK = 32;
static constexpr int META_SLOTOF = 32 + SLOT_CAP;

__device__ __forceinline__ u16 f2bf(float f) {
  u32 u = __builtin_bit_cast(u32, f);
  u32 r = (u + 0x7fffu + ((u >> 16) & 1u)) >> 16;
  return (u16)r;
}
__device__ __forceinline__ float bf2f(u16 h) {
  return __builtin_bit_cast(float, (u32)h << 16);
}

// ---------------- router ----------------
__global__ void router_count(const int* __restrict__ eidx, int* __restrict__ meta) {
  __shared__ int cnt[NEXP];
  const int tid = threadIdx.x;
  if (tid < NEXP) cnt[tid] = 0;
  __syncthreads();
  for (int i = tid; i < T_TOK * TOPK; i += 256) atomicAdd(&cnt[eidx[i]], 1);
  __syncthreads();
  if (tid == 0) {
    int off = 0;
    for (int e = 0; e < NEXP; ++e) {
      int c = cnt[e];
      meta[e] = c;
      meta[8 + e] = off;
      meta[17 + e] = off;
      off += (c + 255) & ~255;      // 256-aligned regions (BM=256)
    }
    meta[16] = off;
  }
}

__global__ void toklist_init(int* __restrict__ meta) {
  const int i = blockIdx.x * 256 + threadIdx.x;
  if (i < SLOT_CAP) meta[META_TOK + i] = 0;   // pad rows use token 0
}

__global__ void router_assign(const int* __restrict__ eidx, int* __restrict__ meta) {
  const int t = blockIdx.x * 256 + threadIdx.x;
  if (t >= T_TOK) return;
  int* cursors = meta + 17;
  int* toklist = meta + META_TOK;
  int* slot_of = meta + META_SLOTOF;
  for (int k = 0; k < TOPK; ++k) {
    const int e = eidx[t * TOPK + k];
    const int pos = atomicAdd(&cursors[e], 1);
    toklist[pos] = t;
    slot_of[t * TOPK + k] = pos;
  }
}

// ---------------- dequant / cast ----------------
template <int CPR>
__global__ void dequant_k(const int* __restrict__ p, const float* __restrict__ s,
                          u16* __restrict__ w) {
  const int gid = blockIdx.x * 256 + threadIdx.x;
  const int row = gid / CPR;
  const int cid = gid % CPR;
  const int4 pk = *(const int4*)(p + (size_t)gid * 4);
  const float sc = s[(size_t)row * (CPR / 4) + (cid >> 2)];
  int v[4] = {pk.x, pk.y, pk.z, pk.w};
  u16x8 o;
#pragma unroll
  for (int b = 0; b < 4; ++b) {
    o[2 * b]     = f2bf((float)((v[b] & 15) - 8) * sc);
    o[2 * b + 1] = f2bf((float)(((v[b] >> 4) & 15) - 8) * sc);
  }
  *(u16x8*)(w + (size_t)gid * 8) = o;
}

__global__ void cast_x_k(const float* __restrict__ x, u16* __restrict__ xb) {
  const int i = (blockIdx.x * 256 + threadIdx.x) * 8;
  const float4 a = *(const float4*)(x + i);
  const float4 b = *(const float4*)(x + i + 4);
  u16x8 o;
  o[0] = f2bf(a.x); o[1] = f2bf(a.y); o[2] = f2bf(a.z); o[3] = f2bf(a.w);
  o[4] = f2bf(b.x); o[5] = f2bf(b.y); o[6] = f2bf(b.z); o[7] = f2bf(b.w);
  *(u16x8*)(xb + i) = o;
}

// ------------- grouped GEMM, 256x256, 8-phase counted-vmcnt schedule -------------
// C[slot, n] = sum_k A[row(slot), k] * B[n, k]   (B is K-major / B^T)
// BM=BN=256, BK=64, 8 waves (2M x 4N), wave tile 128x64, dbuf LDS 2x64KB.
// R5 post-mortem: per-K-tile vmcnt(0) drain (stage issued ~600cy before a
// 900cy-latency wait) capped MfmaUtil at 22%. This round: m201's 8-phase
// schedule — 2 K-tiles/iter; per phase {ds_read subtile | 2 stage loads ->
// s_barrier -> lgkmcnt(0)+sched_barrier(0) -> setprio(1) 16 MFMA setprio(0)
// -> s_barrier}; counted vmcnt(6) at P4 / vmcnt(8) at P8 ONLY (queue never
// drains). Stage loads for an LDS region are issued strictly after the phase
// that last ds_reads that region (A02>=P2, B>=P3, A13>=P5; +4 for buf1), so
// in-flight writes can never land on not-yet-read data. Stage indices wrap
// (&(NT-1)) in the last iterations -> harmless redundant loads, uniform counts.
// LDS layout: packed 1KB 16x32-bf16 subtiles, XOR swizzle o^=((o>>8)&3)<<4;
// global source pre-swizzled (m173). GUP: GEMM1 fuses silu(gate)*up epilogue.
template <int KT, bool GATHER, bool GUP>
__global__ __launch_bounds__(512, 2) void gemm256(const u16* __restrict__ A,
                                                  const u16* __restrict__ B,
                                                  u16* __restrict__ Cout,
                                                  const int* __restrict__ meta) {
  static constexpr int NT = KT / 64;
  static constexpr int OSTR = GUP ? INTER : HID;

  // bid = nt*40 + mt -> XCD = mt%8: the 8 nt-blocks sharing one mt's gathered
  // A-panel colocate on one XCD's L2.
  const int bid = blockIdx.x;
  const int mt = bid % NT_M;
  const int nt = bid / NT_M;
  const int slot0 = mt * 256;
  if (slot0 >= meta[16]) return;
  int e = 0;
#pragma unroll
  for (int i = 1; i < NEXP; ++i) e += (slot0 >= meta[8 + i]);
  const int tid = threadIdx.x;

  __shared__ u16 lds[2 * 32768];   // 2 x (A 32KB + B 32KB)
  char* ldsB = (char*)lds;

  const u16* Be = B + (size_t)e * 2048 * KT;
  const int* toklist = meta + META_TOK;

  // staging sources: 4 A-chunks + 4 B-chunks of 16B per thread; chunk j covers
  // panel rows 64j..64j+63. dest linear L -> subtile S=L>>10, o=(L&1023)^swz;
  // row r=(S>>1)*16+(o>>6), col byte cb=(S&1)*64+(o&63).
  const u16* asrc[4];
  const u16* bsrc[4];
#pragma unroll
  for (int j = 0; j < 4; ++j) {
    const int L = j * 8192 + tid * 16;
    const int S = L >> 10;
    int o = L & 1023;
    o ^= ((o >> 8) & 3) << 4;
    const int r = (S >> 1) * 16 + (o >> 6);
    const int cb = (S & 1) * 64 + (o & 63);
    const int arow = GATHER ? toklist[slot0 + r] : (slot0 + r);
    asrc[j] = A + (size_t)arow * KT + (cb >> 1);
    int brow;
    if (GUP) {
      const int g = r >> 6, j6 = r & 63;
      brow = nt * 128 + g * 32 + (j6 & 31) + ((j6 >> 5) << 10);  // gate | up+1024
    } else {
      brow = nt * 256 + r;
    }
    bsrc[j] = Be + (size_t)brow * KT + (cb >> 1);
  }

#define STG_A(kt_, c_, j_)                                                          \
  __builtin_amdgcn_global_load_lds(                                                 \
      (const __attribute__((address_space(1))) void*)(asrc[j_] + (kt_) * 64),       \
      (__attribute__((address_space(3))) void*)(ldsB + (c_) * 65536 + (j_) * 8192 + \
                                                tid * 16),                           \
      16, 0, 0)
#define STG_B(kt_, c_, j_)                                                          \
  __builtin_amdgcn_global_load_lds(                                                 \
      (const __attribute__((address_space(1))) void*)(bsrc[j_] + (kt_) * 64),       \
      (__attribute__((address_space(3))) void*)(ldsB + (c_) * 65536 + 32768 +       \
                                                (j_) * 8192 + tid * 16),             \
      16, 0, 0)

  const int lane = tid & 63;
  const int wid = tid >> 6;
  const int wm = (wid >> 2) * 128;   // 2 M-groups of 128
  const int wn = (wid & 3) * 64;     // 4 N-groups of 64
  const int fr = lane & 15;
  const int qq = lane >> 4;
  const int swz = (qq * 16) ^ (((fr >> 2) & 3) << 4);

  // fragment bases; per-fragment deltas are compile-time -> fold into ds_read
  // 16-bit offset immediates.
  const int abase = (wm >> 4) * 2048 + fr * 64 + swz;
  const int bbase = 32768 + (wn >> 4) * 2048 + fr * 64 + swz;

  f32x4 acc[8][4];
#pragma unroll
  for (int m = 0; m < 8; ++m)
#pragma unroll
    for (int n = 0; n < 4; ++n) acc[m][n] = (f32x4)0.0f;

  bf16x8 af[4][2], b01[2][2], b23[2][2];

#define BARRIER asm volatile("s_barrier" ::: "memory")
#define LGKM0                                              \
  do {                                                     \
    asm volatile("s_waitcnt lgkmcnt(0)" ::: "memory");     \
    __builtin_amdgcn_sched_barrier(0);                     \
  } while (0)

#define DS_AF(c_, mh_)                                                              \
  _Pragma("unroll") for (int mf = 0; mf < 4; ++mf)                                  \
  _Pragma("unroll") for (int ks = 0; ks < 2; ++ks)                                  \
      af[mf][ks] = *(const bf16x8*)(ldsB + (c_) * 65536 + abase + (mh_) * 8192 +    \
                                    mf * 2048 + ks * 1024);
#define DS_B(c_, bh_, BV_)                                                          \
  _Pragma("unroll") for (int nf = 0; nf < 2; ++nf)                                  \
  _Pragma("unroll") for (int ks = 0; ks < 2; ++ks)                                  \
      BV_[nf][ks] = *(const bf16x8*)(ldsB + (c_) * 65536 + bbase +                  \
                                     ((bh_) * 2 + nf) * 2048 + ks * 1024);
#define MFMA16(mh_, bh_, BV_)                                                       \
  do {                                                                              \
    __builtin_amdgcn_s_setprio(1);                                                  \
    _Pragma("unroll") for (int mf = 0; mf < 4; ++mf)                                \
    _Pragma("unroll") for (int nf = 0; nf < 2; ++nf)                                \
    _Pragma("unroll") for (int ks = 0; ks < 2; ++ks)                                \
        acc[(mh_) * 4 + mf][(bh_) * 2 + nf] =                                       \
            __builtin_amdgcn_mfma_f32_16x16x32_bf16(                                \
                af[mf][ks], BV_[nf][ks], acc[(mh_) * 4 + mf][(bh_) * 2 + nf],       \
                0, 0, 0);                                                           \
    __builtin_amdgcn_s_setprio(0);                                                  \
  } while (0)

  // prologue: tiles 0 (buf0) and 1 (buf1), 16 loads; certify tile0 only.
  STG_A(0, 0, 0); STG_A(0, 0, 2); STG_B(0, 0, 0); STG_B(0, 0, 1);
  STG_B(0, 0, 2); STG_B(0, 0, 3); STG_A(0, 0, 1); STG_A(0, 0, 3);
  STG_A(1, 1, 0); STG_A(1, 1, 2); STG_B(1, 1, 0); STG_B(1, 1, 1);
  STG_B(1, 1, 2); STG_B(1, 1, 3); STG_A(1, 1, 1); STG_A(1, 1, 3);
  asm volatile("s_waitcnt vmcnt(8)" ::: "memory");
  BARRIER;

#pragma unroll 1
  for (int it = 0; it < NT / 2; ++it) {
    const int s0 = (2 * it + 2) & (NT - 1);   // next buf0 tile (wraps: redundant loads)
    const int s1 = (2 * it + 3) & (NT - 1);   // next buf1 tile
    // ---- P1: read af0+b01(buf0); MFMA mh0 x n01 ----
    DS_AF(0, 0); DS_B(0, 0, b01);
    BARRIER; LGKM0; MFMA16(0, 0, b01); BARRIER;
    // ---- P2: read b23(buf0); stage s0.A02; MFMA mh0 x n23 ----
    DS_B(0, 1, b23); STG_A(s0, 0, 0); STG_A(s0, 0, 2);
    BARRIER; LGKM0; MFMA16(0, 1, b23); BARRIER;
    // ---- P3: read af1(buf0); stage s0.B01; MFMA mh1 x n01 ----
    DS_AF(0, 1); STG_B(s0, 0, 0); STG_B(s0, 0, 1);
    BARRIER; LGKM0; MFMA16(1, 0, b01); BARRIER;
    // ---- P4: stage s0.B23; MFMA mh1 x n23; vmcnt(6) certifies tile(buf1) ----
    STG_B(s0, 0, 2); STG_B(s0, 0, 3);
    BARRIER; MFMA16(1, 1, b23);
    asm volatile("s_waitcnt vmcnt(6)" ::: "memory");
    BARRIER;
    // ---- P5: read af0+b01(buf1); stage s0.A13; MFMA mh0 x n01 ----
    DS_AF(1, 0); DS_B(1, 0, b01); STG_A(s0, 0, 1); STG_A(s0, 0, 3);
    BARRIER; LGKM0; MFMA16(0, 0, b01); BARRIER;
    // ---- P6: read b23(buf1); stage s1.A02; MFMA mh0 x n23 ----
    DS_B(1, 1, b23); STG_A(s1, 1, 0); STG_A(s1, 1, 2);
    BARRIER; LGKM0; MFMA16(0, 1, b23); BARRIER;
    // ---- P7: read af1(buf1); stage s1.B all; MFMA mh1 x n01 ----
    DS_AF(1, 1); STG_B(s1, 1, 0); STG_B(s1, 1, 1); STG_B(s1, 1, 2); STG_B(s1, 1, 3);
    BARRIER; LGKM0; MFMA16(1, 0, b01); BARRIER;
    // ---- P8: stage s1.A13; MFMA mh1 x n23; vmcnt(8) certifies next buf0 ----
    STG_A(s1, 1, 1); STG_A(s1, 1, 3);
    BARRIER; MFMA16(1, 1, b23);
    asm volatile("s_waitcnt vmcnt(8)" ::: "memory");
    BARRIER;
  }
#undef STG_A
#undef STG_B
#undef BARRIER
#undef LGKM0
#undef DS_AF
#undef DS_B
#undef MFMA16

  // epilogue: C/D layout col=lane&15, row=(lane>>4)*4+j  [m89-verified]
  if (GUP) {
    // h[row, nt*128 + g*32 + n*16 + fr] = silu(acc[m][n]) * acc[m][n+2], n in {0,1}
    const int g = wid & 3;
#pragma unroll
    for (int mi = 0; mi < 8; ++mi)
#pragma unroll
      for (int n = 0; n < 2; ++n)
#pragma unroll
        for (int jj = 0; jj < 4; ++jj) {
          const float gv = acc[mi][n][jj];
          const float uv = acc[mi][n + 2][jj];
          const float hv = gv / (1.0f + __expf(-gv)) * uv;
          const int row = slot0 + wm + mi * 16 + qq * 4 + jj;
          Cout[(size_t)row * OSTR + nt * 128 + g * 32 + n * 16 + fr] = f2bf(hv);
        }
  } else {
#pragma unroll
    for (int mi = 0; mi < 8; ++mi)
#pragma unroll
      for (int n = 0; n < 4; ++n)
#pragma unroll
        for (int jj = 0; jj < 4; ++jj) {
          const int row = slot0 + wm + mi * 16 + qq * 4 + jj;
          const int col = nt * 256 + wn + n * 16 + fr;
          Cout[(size_t)row * OSTR + col] = f2bf(acc[mi][n][jj]);
        }
  }
}

// ---------------- combine ----------------
__global__ void combine_k(const u16* __restrict__ yp, const float* __restrict__ ew,
                          const int* __restrict__ meta, float* __restrict__ out) {
  const int idx = blockIdx.x * 256 + threadIdx.x;
  const int t = idx >> 8;
  const int pos = (idx & 255) * 8;
  const int* slot_of = meta + META_SLOTOF;
  const int s0 = slot_of[t * 2];
  const int s1 = slot_of[t * 2 + 1];
  const float w0 = ew[t * 2];
  const float w1 = ew[t * 2 + 1];
  const u16x8 v0 = *(const u16x8*)(yp + (size_t)s0 * 2048 + pos);
  const u16x8 v1 = *(const u16x8*)(yp + (size_t)s1 * 2048 + pos);
  float* dst = out + (size_t)t * 2048 + pos;
  float4 o0, o1;
  o0.x = w0 * bf2f(v0[0]) + w1 * bf2f(v1[0]);
  o0.y = w0 * bf2f(v0[1]) + w1 * bf2f(v1[1]);
  o0.z = w0 * bf2f(v0[2]) + w1 * bf2f(v1[2]);
  o0.w = w0 * bf2f(v0[3]) + w1 * bf2f(v1[3]);
  o1.x = w0 * bf2f(v0[4]) + w1 * bf2f(v1[4]);
  o1.y = w0 * bf2f(v0[5]) + w1 * bf2f(v1[5]);
  o1.z = w0 * bf2f(v0[6]) + w1 * bf2f(v1[6]);
  o1.w = w0 * bf2f(v0[7]) + w1 * bf2f(v1[7]);
  *(float4*)dst = o0;
  *(float4*)(dst + 4) = o1;
}

// ---------------- launch ----------------
extern "C" void kernel_launch(void* const* d_in, const int* in_sizes, int n_in,
                              void* d_out, int out_size, void* d_ws, size_t ws_size,
                              hipStream_t stream) {
  const float* x    = (const float*)d_in[0];
  const int*   w1   = (const int*)d_in[1];
  const float* w1s  = (const float*)d_in[2];
  const int*   w2   = (const int*)d_in[3];
  const float* w2s  = (const float*)d_in[4];
  const float* ew   = (const float*)d_in[5];
  const int*   eidx = (const int*)d_in[6];
  float* out = (float*)d_out;

  char* ws = (char*)d_ws;
  // ws layout (bytes); yp reuses W1b's region (dead after GEMM1)
  const size_t OFF_W1B  = 0;           // 8*2048*2048*2 = 67,108,864  (also yp: 10240*2048*2)
  const size_t OFF_W2B  = 67108864;    // 8*2048*1024*2 = 33,554,432
  const size_t OFF_XB   = 100663296;   // 4096*2048*2   = 16,777,216
  const size_t OFF_H    = 117440512;   // 10240*1024*2  = 20,971,520
  const size_t OFF_META = 138412032;   // 18464*4       = 73,856
  const size_t NEED     = 138485888;
  if (ws_size < NEED) return;

  u16* W1b  = (u16*)(ws + OFF_W1B);
  u16* yp   = (u16*)(ws + OFF_W1B);
  u16* W2b  = (u16*)(ws + OFF_W2B);
  u16* xb   = (u16*)(ws + OFF_XB);
  u16* hbuf = (u16*)(ws + OFF_H);
  int* meta = (int*)(ws + OFF_META);

  router_count<<<1, 256, 0, stream>>>(eidx, meta);
  toklist_init<<<SLOT_CAP / 256, 256, 0, stream>>>(meta);
  router_assign<<<T_TOK / 256, 256, 0, stream>>>(eidx, meta);

  cast_x_k<<<(T_TOK * HID) / (256 * 8), 256, 0, stream>>>(x, xb);
  dequant_k<256><<<16384 * 256 / 256, 256, 0, stream>>>(w1, w1s, W1b);
  dequant_k<128><<<16384 * 128 / 256, 256, 0, stream>>>(w2, w2s, W2b);

  // GEMM1 (+fused silu): hbuf[slot, 0..1024) ; grid bid = nt*40+mt, 8 n-tiles
  gemm256<2048, true, true><<<NT_M * 8, 512, 0, stream>>>(xb, W1b, hbuf, meta);
  // GEMM2: yp[slot, 0..2048) = h . W2^T  (K=1024); yp overlays W1b region
  gemm256<1024, false, false><<<NT_M * 8, 512, 0, stream>>>(hbuf, W2b, yp, meta);

  combine_k<<<(T_TOK * HID) / (256 * 8), 256, 0, stream>>>(yp, ew, meta, out);
}